// Round 1
// baseline (1095.525 us; speedup 1.0000x reference)
//
#include <hip/hip_runtime.h>
#include <hip/hip_bf16.h>
#include <math.h>

// Problem constants (fixed by the reference)
#define BATCH 128
#define FDIM  1536
#define GRP   8192
#define LBL   82
#define HDIM  300
#define TOPK  10
#define CAND  (TOPK * LBL)        // 820

// ---------------- fp32 GEMM:  C[M=128, N] = A[128,K] * B[N,K]^T + bias ----
// A row-major [128, 1536], B row-major [N, 1536] (both K-contiguous, "NT").
#define KDIM 1536
#define BM 128
#define BN 32
#define BK 32
#define LDA 132   // BM+4 floats -> 528 B row stride (16B-aligned)
#define LDB 36    // BN+4 floats -> 144 B row stride (16B-aligned)

__global__ __launch_bounds__(256) void gemm_nt_f32(
    const float* __restrict__ A, const float* __restrict__ B,
    const float* __restrict__ bias, float* __restrict__ C,
    int N, int ldc)
{
  __shared__ float As[2][BK][LDA];   // transposed: As[k][m]
  __shared__ float Bs[2][BK][LDB];   // transposed: Bs[k][n]
  const int t  = threadIdx.x;
  const int tx = t & 7;     // 0..7  -> 4 cols each
  const int ty = t >> 3;    // 0..31 -> 4 rows each (also used as load row/col)
  const int n0 = blockIdx.x * BN;

  float4 ra[4];
  float4 rb;

  float acc[4][4] = {{0.f}};

  // prologue load (k0 = 0)
  {
    const int k0 = 0;
#pragma unroll
    for (int it = 0; it < 4; ++it) {
      const int m = ty + 32 * it;
      ra[it] = *reinterpret_cast<const float4*>(A + (size_t)m * KDIM + k0 + 4 * tx);
    }
    int ng  = n0 + ty;
    int ngc = ng < N ? ng : N - 1;      // clamp: OOB rows never stored
    rb = *reinterpret_cast<const float4*>(B + (size_t)ngc * KDIM + k0 + 4 * tx);
  }
  // store to LDS buf 0
  {
#pragma unroll
    for (int it = 0; it < 4; ++it) {
      const int m = ty + 32 * it;
      As[0][4 * tx + 0][m] = ra[it].x;
      As[0][4 * tx + 1][m] = ra[it].y;
      As[0][4 * tx + 2][m] = ra[it].z;
      As[0][4 * tx + 3][m] = ra[it].w;
    }
    Bs[0][4 * tx + 0][ty] = rb.x;
    Bs[0][4 * tx + 1][ty] = rb.y;
    Bs[0][4 * tx + 2][ty] = rb.z;
    Bs[0][4 * tx + 3][ty] = rb.w;
  }
  __syncthreads();

  const int NIT = KDIM / BK;   // 48
  for (int iter = 0; iter < NIT; ++iter) {
    const int buf = iter & 1;
    const bool more = (iter + 1) < NIT;
    if (more) {
      const int k0 = (iter + 1) * BK;
#pragma unroll
      for (int it = 0; it < 4; ++it) {
        const int m = ty + 32 * it;
        ra[it] = *reinterpret_cast<const float4*>(A + (size_t)m * KDIM + k0 + 4 * tx);
      }
      int ng  = n0 + ty;
      int ngc = ng < N ? ng : N - 1;
      rb = *reinterpret_cast<const float4*>(B + (size_t)ngc * KDIM + k0 + 4 * tx);
    }

#pragma unroll
    for (int kk = 0; kk < BK; ++kk) {
      const float4 a  = *reinterpret_cast<const float4*>(&As[buf][kk][4 * ty]);
      const float4 bv = *reinterpret_cast<const float4*>(&Bs[buf][kk][4 * tx]);
      acc[0][0] += a.x * bv.x; acc[0][1] += a.x * bv.y; acc[0][2] += a.x * bv.z; acc[0][3] += a.x * bv.w;
      acc[1][0] += a.y * bv.x; acc[1][1] += a.y * bv.y; acc[1][2] += a.y * bv.z; acc[1][3] += a.y * bv.w;
      acc[2][0] += a.z * bv.x; acc[2][1] += a.z * bv.y; acc[2][2] += a.z * bv.z; acc[2][3] += a.z * bv.w;
      acc[3][0] += a.w * bv.x; acc[3][1] += a.w * bv.y; acc[3][2] += a.w * bv.z; acc[3][3] += a.w * bv.w;
    }

    if (more) {
      const int nb = buf ^ 1;
#pragma unroll
      for (int it = 0; it < 4; ++it) {
        const int m = ty + 32 * it;
        As[nb][4 * tx + 0][m] = ra[it].x;
        As[nb][4 * tx + 1][m] = ra[it].y;
        As[nb][4 * tx + 2][m] = ra[it].z;
        As[nb][4 * tx + 3][m] = ra[it].w;
      }
      Bs[nb][4 * tx + 0][ty] = rb.x;
      Bs[nb][4 * tx + 1][ty] = rb.y;
      Bs[nb][4 * tx + 2][ty] = rb.z;
      Bs[nb][4 * tx + 3][ty] = rb.w;
    }
    __syncthreads();
  }

  // epilogue: C[m, n0+4*tx .. +3] for m = 4*ty..4*ty+3
#pragma unroll
  for (int i = 0; i < 4; ++i) {
    const int m = 4 * ty + i;
    const int n = n0 + 4 * tx;
    if (n + 3 < N) {
      float4 o;
      o.x = acc[i][0] + bias[n + 0];
      o.y = acc[i][1] + bias[n + 1];
      o.z = acc[i][2] + bias[n + 2];
      o.w = acc[i][3] + bias[n + 3];
      *reinterpret_cast<float4*>(C + (size_t)m * ldc + n) = o;
    } else {
#pragma unroll
      for (int j = 0; j < 4; ++j)
        if (n + j < N) C[(size_t)m * ldc + n + j] = acc[i][j] + bias[n + j];
    }
  }
}

// ---------------- top-k (k=10) per row over 8192 group logits -------------
// jax.lax.top_k semantics: sorted descending by value, ties -> lower index.
__global__ __launch_bounds__(256) void topk_kernel(
    const float* __restrict__ logits,      // [128, 8192]
    int*   __restrict__ topk_idx,          // [128, 10]
    float* __restrict__ topk_score)        // [128, 10] (sigmoid of logit)
{
  const int b = blockIdx.x;
  __shared__ float vals[GRP];
  __shared__ unsigned long long red[256];

  {
    const float4* src = reinterpret_cast<const float4*>(logits + (size_t)b * GRP);
    float4* dst = reinterpret_cast<float4*>(vals);
    for (int i = threadIdx.x; i < GRP / 4; i += 256) dst[i] = src[i];
  }
  __syncthreads();

  for (int k = 0; k < TOPK; ++k) {
    unsigned long long best = 0ull;
    for (int i = threadIdx.x; i < GRP; i += 256) {
      unsigned u = __float_as_uint(vals[i]);
      u ^= (u >> 31) ? 0xFFFFFFFFu : 0x80000000u;   // orderable encoding
      unsigned long long key =
          ((unsigned long long)u << 32) | (unsigned)(GRP - 1 - i);  // ties -> lower i
      best = key > best ? key : best;
    }
    red[threadIdx.x] = best;
    __syncthreads();
    for (int s = 128; s > 0; s >>= 1) {
      if (threadIdx.x < s) {
        if (red[threadIdx.x + s] > red[threadIdx.x]) red[threadIdx.x] = red[threadIdx.x + s];
      }
      __syncthreads();
    }
    const unsigned long long w = red[0];
    const int idx = (GRP - 1) - (int)(w & 0xFFFFFFFFu);
    if (threadIdx.x == 0) {
      const float lv = vals[idx];
      topk_idx[b * TOPK + k]   = idx;
      topk_score[b * TOPK + k] = 1.0f / (1.0f + expf(-lv));
      vals[idx] = -INFINITY;     // remove winner
    }
    __syncthreads();
  }
}

// ---------------- candidate scoring: one wave per (b, candidate) ----------
__global__ __launch_bounds__(256) void score_kernel(
    const int*   __restrict__ group_labels,  // [G*L] (int32 on device)
    const float* __restrict__ embed,         // [N_LABELS, 300]
    const float* __restrict__ emb,           // [128, 300]
    const int*   __restrict__ topk_idx,      // [128, 10]
    const float* __restrict__ topk_score,    // [128, 10]
    float* __restrict__ out_cand,            // [128*820]
    float* __restrict__ out_scores)          // [128*820]
{
  const int wave = (int)((blockIdx.x * 256u + threadIdx.x) >> 6);
  const int lane = threadIdx.x & 63;
  const int total = BATCH * CAND;
  if (wave >= total) return;

  const int b  = wave / CAND;
  const int cc = wave - b * CAND;
  const int k  = cc / LBL;
  const int l  = cc - k * LBL;

  const int g     = topk_idx[b * TOPK + k];
  const int label = group_labels[(size_t)g * LBL + l];

  const float* erow = embed + (size_t)label * HDIM;
  const float* v    = emb + (size_t)b * HDIM;

  float s = 0.f;
  for (int h = lane; h < HDIM; h += 64) s += erow[h] * v[h];
#pragma unroll
  for (int off = 32; off > 0; off >>= 1) s += __shfl_down(s, off, 64);

  if (lane == 0) {
    const float sc = (1.0f / (1.0f + expf(-s))) * topk_score[b * TOPK + k];
    out_cand[wave]   = (float)label;   // harness reads flat f32; index < 2^24 exact
    out_scores[wave] = sc;
  }
}

extern "C" void kernel_launch(void* const* d_in, const int* in_sizes, int n_in,
                              void* d_out, int out_size, void* d_ws, size_t ws_size,
                              hipStream_t stream) {
  const float* x     = (const float*)d_in[0];   // out  [128,1536]
  const float* W0    = (const float*)d_in[1];   // [8192,1536]
  const float* b0    = (const float*)d_in[2];   // [8192]
  const float* W1    = (const float*)d_in[3];   // [300,1536]
  const float* b1    = (const float*)d_in[4];   // [300]
  const float* embed = (const float*)d_in[5];   // [671744,300]
  const int*   glab  = (const int*)d_in[6];     // [8192*82]
  // d_in[7] = candidates_topk scalar (K=10, hardcoded)

  float* gl       = (float*)d_out;              // [128*8192]
  float* out_cand = gl + BATCH * GRP;           // [128*820]
  float* out_sc   = out_cand + BATCH * CAND;    // [128*820]

  char* ws = (char*)d_ws;
  int*   topk_idx   = (int*)ws;                            // 1280 ints
  float* topk_score = (float*)(ws + 1280 * sizeof(int));   // 1280 floats
  float* emb        = (float*)(ws + 2 * 1280 * 4);         // 128*300 floats

  // K1: group logits GEMM (N=8192) -> d_out segment 0
  gemm_nt_f32<<<GRP / BN, 256, 0, stream>>>(x, W0, b0, gl, GRP, GRP);
  // K3: emb GEMM (N=300) -> workspace
  gemm_nt_f32<<<(HDIM + BN - 1) / BN, 256, 0, stream>>>(x, W1, b1, emb, HDIM, HDIM);
  // K2: top-10 per row
  topk_kernel<<<BATCH, 256, 0, stream>>>(gl, topk_idx, topk_score);
  // K4: candidate expansion + embedding dot + sigmoid*prior
  const int total_waves = BATCH * CAND;                 // 104960
  const int blocks = (total_waves + 3) / 4;             // 4 waves/block
  score_kernel<<<blocks, 256, 0, stream>>>(glab, embed, emb, topk_idx, topk_score,
                                           out_cand, out_sc);
}